// Round 3
// baseline (234.671 us; speedup 1.0000x reference)
//
#include <hip/hip_runtime.h>
#include <hip/hip_cooperative_groups.h>
#include <math.h>

namespace cg = cooperative_groups;

#define NUM_CLASSES 1000
#define FEAT_DIM    512
#define BATCH       32768
#define LAMDA       0.5f
#define EPS         1e-8f

#define GRID 1024             // 4 blocks/CU x 256 CUs -> co-resident for grid.sync
#define SB   50               // centers-pass blocks
#define CB   (GRID - SB)      // 974 center-loss blocks
#define ROWS_PER_BLOCK 20     // 50*20 = 1000 center rows
#define HALF4 (BATCH * FEAT_DIM / 8)   // 2097152 float4s per half

// ws layout (floats):
//   [0, 50*512)      s partials (per centers-block weighted column sums)
#define DIAG_OFF 25600   // [25600, 25650)  diag partials
#define CL_OFF   26624   // [26624, 26624+CB) center-loss partials

__global__ __launch_bounds__(256, 4) void k_all(const float* __restrict__ feat,
                                                const float* __restrict__ centers,
                                                const int* __restrict__ label,
                                                float* __restrict__ ws,
                                                float* __restrict__ out) {
    __shared__ float s_sh[4][512];
    __shared__ float d_sh[4];
    __shared__ float sm[4];
    const int t = threadIdx.x;
    const int w = t >> 6, l = t & 63;

    if (blockIdx.x < SB) {
        // ---- centers pass: row norms -> inv, s += c*inv, diag += n2*inv^2 ----
        const float4* c4 = (const float4*)centers;
        const int j0 = blockIdx.x * ROWS_PER_BLOCK;
        float4 sa = make_float4(0.f, 0.f, 0.f, 0.f);
        float4 sb = make_float4(0.f, 0.f, 0.f, 0.f);
        float diag = 0.f;
        for (int r = w; r < ROWS_PER_BLOCK; r += 4) {  // 5 rows per wave
            const int j = j0 + r;
            const float4 a = c4[j * 128 + l];
            const float4 b = c4[j * 128 + 64 + l];
            float n2 = a.x*a.x + a.y*a.y + a.z*a.z + a.w*a.w
                     + b.x*b.x + b.y*b.y + b.z*b.z + b.w*b.w;
            for (int o = 32; o > 0; o >>= 1) n2 += __shfl_xor(n2, o, 64);
            const float inv = 1.0f / fmaxf(sqrtf(n2), EPS);
            sa.x += a.x * inv; sa.y += a.y * inv; sa.z += a.z * inv; sa.w += a.w * inv;
            sb.x += b.x * inv; sb.y += b.y * inv; sb.z += b.z * inv; sb.w += b.w * inv;
            diag += n2 * inv * inv;   // identical in all lanes
        }
        s_sh[w][4*l+0] = sa.x; s_sh[w][4*l+1] = sa.y;
        s_sh[w][4*l+2] = sa.z; s_sh[w][4*l+3] = sa.w;
        s_sh[w][256+4*l+0] = sb.x; s_sh[w][256+4*l+1] = sb.y;
        s_sh[w][256+4*l+2] = sb.z; s_sh[w][256+4*l+3] = sb.w;
        if (l == 0) d_sh[w] = diag;
        __syncthreads();
        const float v0 = s_sh[0][t] + s_sh[1][t] + s_sh[2][t] + s_sh[3][t];
        const float v1 = s_sh[0][t+256] + s_sh[1][t+256] + s_sh[2][t+256] + s_sh[3][t+256];
        ws[blockIdx.x * 512 + t]       = v0;
        ws[blockIdx.x * 512 + 256 + t] = v1;
        if (t == 0)
            ws[DIAG_OFF + blockIdx.x] = d_sh[0] + d_sh[1] + d_sh[2] + d_sh[3];
    } else {
        // ---- center loss: grid-stride over float4s of feat, 2x unrolled ----
        const float4* f4 = (const float4*)feat;
        const float4* c4 = (const float4*)centers;
        const int b      = blockIdx.x - SB;
        const int tid    = b * 256 + t;
        const int stride = CB * 256;
        float acc = 0.f;
        for (int idx = tid; idx < HALF4; idx += stride) {
            const int i1  = idx + HALF4;
            const int lb0 = label[idx >> 7];
            const int lb1 = label[i1  >> 7];
            const float4 f0 = f4[idx];
            const float4 f1 = f4[i1];
            const float4 c0 = c4[lb0 * 128 + (idx & 127)];
            const float4 c1 = c4[lb1 * 128 + (i1  & 127)];
            const float dx0 = f0.x - c0.x, dy0 = f0.y - c0.y, dz0 = f0.z - c0.z, dw0 = f0.w - c0.w;
            const float dx1 = f1.x - c1.x, dy1 = f1.y - c1.y, dz1 = f1.z - c1.z, dw1 = f1.w - c1.w;
            acc += dx0*dx0 + dy0*dy0 + dz0*dz0 + dw0*dw0
                 + dx1*dx1 + dy1*dy1 + dz1*dz1 + dw1*dw1;
        }
        for (int o = 32; o > 0; o >>= 1) acc += __shfl_down(acc, o, 64);
        if (l == 0) sm[w] = acc;
        __syncthreads();
        if (t == 0) ws[CL_OFF + b] = sm[0] + sm[1] + sm[2] + sm[3];
    }

    __threadfence();
    cg::this_grid().sync();

    // ---- final combine: block 0 only (all terms linear in the partials) ----
    if (blockIdx.x == 0) {
        float val = 0.f;
        for (int d = t; d < FEAT_DIM; d += 256) {
            float s_d = 0.f;
#pragma unroll
            for (int bb = 0; bb < SB; ++bb) s_d += ws[bb * FEAT_DIM + d];
            val += s_d * s_d;                       // contributes to ||s||^2
        }
        if (t < SB) val -= ws[DIAG_OFF + t];        // minus diagonal
        val *= LAMDA;
        float clp = 0.f;
        for (int i = t; i < CB; i += 256) clp += ws[CL_OFF + i];
        val += clp * (0.5f / (float)BATCH);

        for (int o = 32; o > 0; o >>= 1) val += __shfl_down(val, o, 64);
        __syncthreads();
        if (l == 0) sm[w] = val;
        __syncthreads();
        if (t == 0)
            out[0] = sm[0] + sm[1] + sm[2] + sm[3]
                   + LAMDA * (float)NUM_CLASSES * (float)(NUM_CLASSES - 1);
    }
}

extern "C" void kernel_launch(void* const* d_in, const int* in_sizes, int n_in,
                              void* d_out, int out_size, void* d_ws, size_t ws_size,
                              hipStream_t stream) {
    const int*   label   = (const int*)d_in[0];
    const float* feat    = (const float*)d_in[1];
    const float* centers = (const float*)d_in[2];
    float* ws  = (float*)d_ws;
    float* out = (float*)d_out;

    void* args[] = {(void*)&feat, (void*)&centers, (void*)&label, (void*)&ws, (void*)&out};
    hipLaunchCooperativeKernel((const void*)k_all, dim3(GRID), dim3(256), args, 0, stream);
}

// Round 4
// 165.553 us; speedup vs baseline: 1.4175x; 1.4175x over previous
//
#include <hip/hip_runtime.h>
#include <math.h>

#define NUM_CLASSES 1000
#define FEAT_DIM    512
#define BATCH       32768
#define LAMDA       0.5f
#define EPS         1e-8f

#define SB   50               // centers-pass blocks
#define CB   2048             // center-loss blocks
#define GRID (SB + CB)        // 2098
#define ROWS_PER_BLOCK 20     // 50*20 = 1000 center rows

// ws layout (floats):
//   [0, 50*512)      s partials (per centers-block weighted column sums)
#define DIAG_OFF 25600   // [25600, 25650)  diag partials
#define CL_OFF   26624   // [26624, 26624+CB) center-loss partials
#define CTR_OFF  28672   // one uint counter

__global__ __launch_bounds__(256) void k_all(const float* __restrict__ feat,
                                             const float* __restrict__ centers,
                                             const int* __restrict__ label,
                                             float* __restrict__ ws,
                                             float* __restrict__ out,
                                             unsigned int* __restrict__ ctr) {
    __shared__ float s_sh[4][512];
    __shared__ float d_sh[4];
    __shared__ float sm[4];
    __shared__ unsigned int is_last;
    const int t = threadIdx.x;
    const int w = t >> 6, l = t & 63;

    if (blockIdx.x < SB) {
        // ---- centers pass: row norms -> inv, s += c*inv, diag += n2*inv^2 ----
        const float4* c4 = (const float4*)centers;
        const int j0 = blockIdx.x * ROWS_PER_BLOCK;
        float4 sa = make_float4(0.f, 0.f, 0.f, 0.f);
        float4 sb = make_float4(0.f, 0.f, 0.f, 0.f);
        float diag = 0.f;
        for (int r = w; r < ROWS_PER_BLOCK; r += 4) {  // 5 rows per wave
            const int j = j0 + r;
            const float4 a = c4[j * 128 + l];
            const float4 b = c4[j * 128 + 64 + l];
            float n2 = a.x*a.x + a.y*a.y + a.z*a.z + a.w*a.w
                     + b.x*b.x + b.y*b.y + b.z*b.z + b.w*b.w;
            for (int o = 32; o > 0; o >>= 1) n2 += __shfl_xor(n2, o, 64);
            const float inv = 1.0f / fmaxf(sqrtf(n2), EPS);
            sa.x += a.x * inv; sa.y += a.y * inv; sa.z += a.z * inv; sa.w += a.w * inv;
            sb.x += b.x * inv; sb.y += b.y * inv; sb.z += b.z * inv; sb.w += b.w * inv;
            diag += n2 * inv * inv;   // identical in all lanes
        }
        s_sh[w][4*l+0] = sa.x; s_sh[w][4*l+1] = sa.y;
        s_sh[w][4*l+2] = sa.z; s_sh[w][4*l+3] = sa.w;
        s_sh[w][256+4*l+0] = sb.x; s_sh[w][256+4*l+1] = sb.y;
        s_sh[w][256+4*l+2] = sb.z; s_sh[w][256+4*l+3] = sb.w;
        if (l == 0) d_sh[w] = diag;
        __syncthreads();
        const float v0 = s_sh[0][t] + s_sh[1][t] + s_sh[2][t] + s_sh[3][t];
        const float v1 = s_sh[0][t+256] + s_sh[1][t+256] + s_sh[2][t+256] + s_sh[3][t+256];
        ws[blockIdx.x * 512 + t]       = v0;
        ws[blockIdx.x * 512 + 256 + t] = v1;
        if (t == 0)
            ws[DIAG_OFF + blockIdx.x] = d_sh[0] + d_sh[1] + d_sh[2] + d_sh[3];
    } else {
        // ---- center loss: grid-stride over float4 elements of feat ----
        const float4* f4 = (const float4*)feat;
        const float4* c4 = (const float4*)centers;
        const int b      = blockIdx.x - SB;
        const int tid    = b * 256 + t;
        const int stride = CB * 256;           // 524288, power of 2
        float acc = 0.f;
        const int total4 = BATCH * FEAT_DIM / 4;  // 4194304
        for (int idx = tid; idx < total4; idx += stride) {
            const int sample = idx >> 7;   // 128 float4 per sample
            const int d4     = idx & 127;
            const int lbl    = label[sample];
            const float4 f = f4[idx];
            const float4 c = c4[lbl * 128 + d4];
            const float dx = f.x - c.x, dy = f.y - c.y, dz = f.z - c.z, dw = f.w - c.w;
            acc += dx * dx + dy * dy + dz * dz + dw * dw;
        }
        for (int o = 32; o > 0; o >>= 1) acc += __shfl_down(acc, o, 64);
        if (l == 0) sm[w] = acc;
        __syncthreads();
        if (t == 0) ws[CL_OFF + b] = sm[0] + sm[1] + sm[2] + sm[3];
    }

    // ---- last-block finish (deterministic: fixed summation order) ----
    __threadfence();                      // release partials (device scope)
    if (t == 0) {
        const unsigned int old = atomicAdd(ctr, 1u);
        is_last = (old == GRID - 1) ? 1u : 0u;
    }
    __syncthreads();
    if (is_last) {
        __threadfence();                  // acquire other blocks' partials

        float val = 0.f;
        for (int d = t; d < FEAT_DIM; d += 256) {
            float s_d = 0.f;
#pragma unroll
            for (int bb = 0; bb < SB; ++bb) s_d += ws[bb * FEAT_DIM + d];
            val += s_d * s_d;                       // ||s||^2 contribution
        }
        if (t < SB) val -= ws[DIAG_OFF + t];        // minus diagonal
        val *= LAMDA;
        float clp = 0.f;
#pragma unroll 8
        for (int i = t; i < CB; i += 256) clp += ws[CL_OFF + i];
        val += clp * (0.5f / (float)BATCH);

        for (int o = 32; o > 0; o >>= 1) val += __shfl_down(val, o, 64);
        __syncthreads();
        if (l == 0) sm[w] = val;
        __syncthreads();
        if (t == 0)
            out[0] = sm[0] + sm[1] + sm[2] + sm[3]
                   + LAMDA * (float)NUM_CLASSES * (float)(NUM_CLASSES - 1);
    }
}

extern "C" void kernel_launch(void* const* d_in, const int* in_sizes, int n_in,
                              void* d_out, int out_size, void* d_ws, size_t ws_size,
                              hipStream_t stream) {
    const int*   label   = (const int*)d_in[0];
    const float* feat    = (const float*)d_in[1];
    const float* centers = (const float*)d_in[2];
    float* ws  = (float*)d_ws;
    float* out = (float*)d_out;
    unsigned int* ctr = (unsigned int*)(ws + CTR_OFF);

    hipMemsetAsync(ctr, 0, sizeof(unsigned int), stream);
    k_all<<<GRID, 256, 0, stream>>>(feat, centers, label, ws, out, ctr);
}

// Round 5
// 49.463 us; speedup vs baseline: 4.7444x; 3.3470x over previous
//
#include <hip/hip_runtime.h>
#include <math.h>

#define NUM_CLASSES 1000
#define FEAT_DIM    512
#define BATCH       32768
#define LAMDA       0.5f
#define EPS         1e-8f

#define SB   50               // centers-pass blocks
#define CB   2048             // center-loss blocks
#define GRID (SB + CB)        // 2098
#define ROWS_PER_BLOCK 20     // 50*20 = 1000 center rows

// ws layout (floats):
//   [0, 50*512)      s partials (per centers-block weighted column sums)
#define DIAG_OFF 25600   // [25600, 25650)  diag partials
#define CL_OFF   26624   // [26624, 26624+CB) center-loss partials
#define CTR_OFF  28672   // one uint counter

// Coherent (LLC / sc1) memory ops — bypass the non-coherent per-XCD L2 so
// cross-XCD visibility needs NO agent-scope fences (R3/R4: fence-per-block
// = L2 writeback storm, ~150us). Deterministic: unique addresses, fixed order.
#define AST(p, v) __hip_atomic_store((p), (v), __ATOMIC_RELAXED, __HIP_MEMORY_SCOPE_AGENT)
#define ALD(p)    __hip_atomic_load((p), __ATOMIC_RELAXED, __HIP_MEMORY_SCOPE_AGENT)

__global__ __launch_bounds__(256) void k_all(const float* __restrict__ feat,
                                             const float* __restrict__ centers,
                                             const int* __restrict__ label,
                                             float* __restrict__ ws,
                                             float* __restrict__ out,
                                             unsigned int* __restrict__ ctr) {
    __shared__ float s_sh[4][512];
    __shared__ float d_sh[4];
    __shared__ float sm[4];
    __shared__ unsigned int is_last;
    const int t = threadIdx.x;
    const int w = t >> 6, l = t & 63;

    if (blockIdx.x < SB) {
        // ---- centers pass: row norms -> inv, s += c*inv, diag += n2*inv^2 ----
        const float4* c4 = (const float4*)centers;
        const int j0 = blockIdx.x * ROWS_PER_BLOCK;
        float4 sa = make_float4(0.f, 0.f, 0.f, 0.f);
        float4 sb = make_float4(0.f, 0.f, 0.f, 0.f);
        float diag = 0.f;
        for (int r = w; r < ROWS_PER_BLOCK; r += 4) {  // 5 rows per wave
            const int j = j0 + r;
            const float4 a = c4[j * 128 + l];
            const float4 b = c4[j * 128 + 64 + l];
            float n2 = a.x*a.x + a.y*a.y + a.z*a.z + a.w*a.w
                     + b.x*b.x + b.y*b.y + b.z*b.z + b.w*b.w;
            for (int o = 32; o > 0; o >>= 1) n2 += __shfl_xor(n2, o, 64);
            const float inv = 1.0f / fmaxf(sqrtf(n2), EPS);
            sa.x += a.x * inv; sa.y += a.y * inv; sa.z += a.z * inv; sa.w += a.w * inv;
            sb.x += b.x * inv; sb.y += b.y * inv; sb.z += b.z * inv; sb.w += b.w * inv;
            diag += n2 * inv * inv;   // identical in all lanes
        }
        s_sh[w][4*l+0] = sa.x; s_sh[w][4*l+1] = sa.y;
        s_sh[w][4*l+2] = sa.z; s_sh[w][4*l+3] = sa.w;
        s_sh[w][256+4*l+0] = sb.x; s_sh[w][256+4*l+1] = sb.y;
        s_sh[w][256+4*l+2] = sb.z; s_sh[w][256+4*l+3] = sb.w;
        if (l == 0) d_sh[w] = diag;
        __syncthreads();
        const float v0 = s_sh[0][t] + s_sh[1][t] + s_sh[2][t] + s_sh[3][t];
        const float v1 = s_sh[0][t+256] + s_sh[1][t+256] + s_sh[2][t+256] + s_sh[3][t+256];
        AST(&ws[blockIdx.x * 512 + t],       v0);
        AST(&ws[blockIdx.x * 512 + 256 + t], v1);
        if (t == 0)
            AST(&ws[DIAG_OFF + blockIdx.x], d_sh[0] + d_sh[1] + d_sh[2] + d_sh[3]);
    } else {
        // ---- center loss: grid-stride over float4 elements of feat ----
        const float4* f4 = (const float4*)feat;
        const float4* c4 = (const float4*)centers;
        const int b      = blockIdx.x - SB;
        const int tid    = b * 256 + t;
        const int stride = CB * 256;           // 524288, power of 2
        float acc = 0.f;
        const int total4 = BATCH * FEAT_DIM / 4;  // 4194304
        for (int idx = tid; idx < total4; idx += stride) {
            const int sample = idx >> 7;   // 128 float4 per sample
            const int d4     = idx & 127;
            const int lbl    = label[sample];
            const float4 f = f4[idx];
            const float4 c = c4[lbl * 128 + d4];
            const float dx = f.x - c.x, dy = f.y - c.y, dz = f.z - c.z, dw = f.w - c.w;
            acc += dx * dx + dy * dy + dz * dz + dw * dw;
        }
        for (int o = 32; o > 0; o >>= 1) acc += __shfl_down(acc, o, 64);
        if (l == 0) sm[w] = acc;
        __syncthreads();
        if (t == 0) AST(&ws[CL_OFF + b], sm[0] + sm[1] + sm[2] + sm[3]);
    }

    // ---- last-block finish, fence-free ----
    // Each thread: own sc1 stores complete at LLC; then block barrier; then one
    // relaxed agent-scope counter bump. No L2 writeback anywhere.
    asm volatile("s_waitcnt vmcnt(0)" ::: "memory");
    __syncthreads();
    if (t == 0) {
        const unsigned int old =
            __hip_atomic_fetch_add(ctr, 1u, __ATOMIC_RELAXED, __HIP_MEMORY_SCOPE_AGENT);
        is_last = (old == GRID - 1) ? 1u : 0u;
    }
    __syncthreads();
    if (is_last) {
        asm volatile("" ::: "memory");   // keep sc1 loads after the ctr win

        float val = 0.f;
        for (int d = t; d < FEAT_DIM; d += 256) {
            float s_d = 0.f;
#pragma unroll
            for (int bb = 0; bb < SB; ++bb) s_d += ALD(&ws[bb * FEAT_DIM + d]);
            val += s_d * s_d;                       // ||s||^2 contribution
        }
        if (t < SB) val -= ALD(&ws[DIAG_OFF + t]);  // minus diagonal
        val *= LAMDA;
        float clp = 0.f;
#pragma unroll 8
        for (int i = t; i < CB; i += 256) clp += ALD(&ws[CL_OFF + i]);
        val += clp * (0.5f / (float)BATCH);

        for (int o = 32; o > 0; o >>= 1) val += __shfl_down(val, o, 64);
        __syncthreads();
        if (l == 0) sm[w] = val;
        __syncthreads();
        if (t == 0)
            out[0] = sm[0] + sm[1] + sm[2] + sm[3]
                   + LAMDA * (float)NUM_CLASSES * (float)(NUM_CLASSES - 1);
    }
}

extern "C" void kernel_launch(void* const* d_in, const int* in_sizes, int n_in,
                              void* d_out, int out_size, void* d_ws, size_t ws_size,
                              hipStream_t stream) {
    const int*   label   = (const int*)d_in[0];
    const float* feat    = (const float*)d_in[1];
    const float* centers = (const float*)d_in[2];
    float* ws  = (float*)d_ws;
    float* out = (float*)d_out;
    unsigned int* ctr = (unsigned int*)(ws + CTR_OFF);

    hipMemsetAsync(ctr, 0, sizeof(unsigned int), stream);
    k_all<<<GRID, 256, 0, stream>>>(feat, centers, label, ws, out, ctr);
}

// Round 6
// 31.286 us; speedup vs baseline: 7.5009x; 1.5810x over previous
//
#include <hip/hip_runtime.h>
#include <math.h>

#define NUM_CLASSES 1000
#define FEAT_DIM    512
#define BATCH       32768
#define LAMDA       0.5f
#define EPS         1e-8f

#define SB   50               // centers-pass blocks
#define CB   2048             // center-loss blocks
#define GRID (SB + CB)        // 2098
#define ROWS_PER_BLOCK 20     // 50*20 = 1000 center rows

// ws layout (floats):
//   [0, 50*512)      s partials (per centers-block weighted column sums)
#define DIAG_OFF 25600   // [25600, 25650)  diag partials
#define CL_OFF   26624   // [26624, 26624+CB) center-loss partials
#define CTR_OFF  32768   // level-1: 64 counters @ stride 16 uints; level-2: 1 uint after
#define NGROUPS  64

// Coherent (LLC / sc1) ops — bypass non-coherent XCD L2; NO agent fences
// (R3/R4 lesson: fence-per-block = L2 writeback storm, ~125us).
// R5 lesson: 2098 same-address device-scope RMWs serialize at one LLC slice
// (~23ns each = 48us) -> two-level counters, 64-way spread.
#define AST(p, v) __hip_atomic_store((p), (v), __ATOMIC_RELAXED, __HIP_MEMORY_SCOPE_AGENT)
#define ALD(p)    __hip_atomic_load((p), __ATOMIC_RELAXED, __HIP_MEMORY_SCOPE_AGENT)

__global__ __launch_bounds__(256) void k_all(const float* __restrict__ feat,
                                             const float* __restrict__ centers,
                                             const int* __restrict__ label,
                                             float* __restrict__ ws,
                                             float* __restrict__ out,
                                             unsigned int* __restrict__ ctr) {
    __shared__ float s_sh[4][512];
    __shared__ float d_sh[4];
    __shared__ float sm[4];
    __shared__ unsigned int is_last;
    const int t = threadIdx.x;
    const int w = t >> 6, l = t & 63;

    if (blockIdx.x < SB) {
        // ---- centers pass: row norms -> inv, s += c*inv, diag += n2*inv^2 ----
        const float4* c4 = (const float4*)centers;
        const int j0 = blockIdx.x * ROWS_PER_BLOCK;
        float4 sa = make_float4(0.f, 0.f, 0.f, 0.f);
        float4 sb = make_float4(0.f, 0.f, 0.f, 0.f);
        float diag = 0.f;
        for (int r = w; r < ROWS_PER_BLOCK; r += 4) {  // 5 rows per wave
            const int j = j0 + r;
            const float4 a = c4[j * 128 + l];
            const float4 b = c4[j * 128 + 64 + l];
            float n2 = a.x*a.x + a.y*a.y + a.z*a.z + a.w*a.w
                     + b.x*b.x + b.y*b.y + b.z*b.z + b.w*b.w;
            for (int o = 32; o > 0; o >>= 1) n2 += __shfl_xor(n2, o, 64);
            const float inv = 1.0f / fmaxf(sqrtf(n2), EPS);
            sa.x += a.x * inv; sa.y += a.y * inv; sa.z += a.z * inv; sa.w += a.w * inv;
            sb.x += b.x * inv; sb.y += b.y * inv; sb.z += b.z * inv; sb.w += b.w * inv;
            diag += n2 * inv * inv;   // identical in all lanes
        }
        s_sh[w][4*l+0] = sa.x; s_sh[w][4*l+1] = sa.y;
        s_sh[w][4*l+2] = sa.z; s_sh[w][4*l+3] = sa.w;
        s_sh[w][256+4*l+0] = sb.x; s_sh[w][256+4*l+1] = sb.y;
        s_sh[w][256+4*l+2] = sb.z; s_sh[w][256+4*l+3] = sb.w;
        if (l == 0) d_sh[w] = diag;
        __syncthreads();
        const float v0 = s_sh[0][t] + s_sh[1][t] + s_sh[2][t] + s_sh[3][t];
        const float v1 = s_sh[0][t+256] + s_sh[1][t+256] + s_sh[2][t+256] + s_sh[3][t+256];
        AST(&ws[blockIdx.x * 512 + t],       v0);
        AST(&ws[blockIdx.x * 512 + 256 + t], v1);
        if (t == 0)
            AST(&ws[DIAG_OFF + blockIdx.x], d_sh[0] + d_sh[1] + d_sh[2] + d_sh[3]);
    } else {
        // ---- center loss: grid-stride over float4 elements of feat ----
        const float4* f4 = (const float4*)feat;
        const float4* c4 = (const float4*)centers;
        const int b      = blockIdx.x - SB;
        const int tid    = b * 256 + t;
        const int stride = CB * 256;           // 524288, power of 2
        float acc = 0.f;
        const int total4 = BATCH * FEAT_DIM / 4;  // 4194304
        for (int idx = tid; idx < total4; idx += stride) {
            const int sample = idx >> 7;   // 128 float4 per sample
            const int d4     = idx & 127;
            const int lbl    = label[sample];
            const float4 f = f4[idx];
            const float4 c = c4[lbl * 128 + d4];
            const float dx = f.x - c.x, dy = f.y - c.y, dz = f.z - c.z, dw = f.w - c.w;
            acc += dx * dx + dy * dy + dz * dz + dw * dw;
        }
        for (int o = 32; o > 0; o >>= 1) acc += __shfl_down(acc, o, 64);
        if (l == 0) sm[w] = acc;
        __syncthreads();
        if (t == 0) AST(&ws[CL_OFF + b], sm[0] + sm[1] + sm[2] + sm[3]);
    }

    // ---- last-block finish: two-level counters, fence-free ----
    asm volatile("s_waitcnt vmcnt(0)" ::: "memory");  // own sc1 stores at LLC
    __syncthreads();                                   // whole block's stores at LLC
    if (t == 0) {
        const int g     = blockIdx.x & (NGROUPS - 1);
        const int gsize = (GRID / NGROUPS) + (g < (GRID % NGROUPS) ? 1 : 0);
        unsigned int done = 0;
        const unsigned int o1 = __hip_atomic_fetch_add(ctr + g * 16, 1u,
                                   __ATOMIC_RELAXED, __HIP_MEMORY_SCOPE_AGENT);
        if (o1 == (unsigned int)(gsize - 1)) {
            const unsigned int o2 = __hip_atomic_fetch_add(ctr + NGROUPS * 16, 1u,
                                       __ATOMIC_RELAXED, __HIP_MEMORY_SCOPE_AGENT);
            done = (o2 == NGROUPS - 1) ? 1u : 0u;
        }
        is_last = done;
    }
    __syncthreads();
    if (is_last) {
        asm volatile("" ::: "memory");   // keep sc1 loads after the ctr win

        float val = 0.f;
        for (int d = t; d < FEAT_DIM; d += 256) {
            float s_d = 0.f;
#pragma unroll
            for (int bb = 0; bb < SB; ++bb) s_d += ALD(&ws[bb * FEAT_DIM + d]);
            val += s_d * s_d;                       // ||s||^2 contribution
        }
        if (t < SB) val -= ALD(&ws[DIAG_OFF + t]);  // minus diagonal
        val *= LAMDA;
        float clp = 0.f;
#pragma unroll 8
        for (int i = t; i < CB; i += 256) clp += ALD(&ws[CL_OFF + i]);
        val += clp * (0.5f / (float)BATCH);

        for (int o = 32; o > 0; o >>= 1) val += __shfl_down(val, o, 64);
        __syncthreads();
        if (l == 0) sm[w] = val;
        __syncthreads();
        if (t == 0)
            out[0] = sm[0] + sm[1] + sm[2] + sm[3]
                   + LAMDA * (float)NUM_CLASSES * (float)(NUM_CLASSES - 1);
    }
}

extern "C" void kernel_launch(void* const* d_in, const int* in_sizes, int n_in,
                              void* d_out, int out_size, void* d_ws, size_t ws_size,
                              hipStream_t stream) {
    const int*   label   = (const int*)d_in[0];
    const float* feat    = (const float*)d_in[1];
    const float* centers = (const float*)d_in[2];
    float* ws  = (float*)d_ws;
    float* out = (float*)d_out;
    unsigned int* ctr = (unsigned int*)(ws + CTR_OFF);

    // zero level-1 (64 x 16 uints) + level-2 (1 uint)
    hipMemsetAsync(ctr, 0, (NGROUPS * 16 + 1) * sizeof(unsigned int), stream);
    k_all<<<GRID, 256, 0, stream>>>(feat, centers, label, ws, out, ctr);
}

// Round 7
// 24.820 us; speedup vs baseline: 9.4548x; 1.2605x over previous
//
#include <hip/hip_runtime.h>
#include <math.h>

#define NUM_CLASSES 1000
#define FEAT_DIM    512
#define BATCH       32768
#define LAMDA       0.5f
#define EPS         1e-8f

// GRID = 2048 exactly: 8 blocks/CU x 256 CU -> one residency round, no straggler
// tail (R2 lesson: 2098 blocks = 50-block serial second round).
#define SB   50               // centers-pass blocks (dispatched first, ~2us)
#define CB   1998             // streaming center-loss blocks
#define GRID (SB + CB)        // 2048
#define ROWS_PER_BLOCK 20     // 50*20 = 1000 center rows
#define TOTAL4  (BATCH * FEAT_DIM / 4)   // 4194304 float4s
#define STRIDE  (CB * 256)               // 511488
#define NCHUNK  9                        // ceil(TOTAL4 / STRIDE)

// ws layout (floats):
//   [0, 50*512)      s partials (per centers-block weighted column sums)
#define DIAG_OFF 25600   // [25600, 25650)  diag partials
#define CL_OFF   26624   // [26624, 26624+CB) center-loss partials

// Two plain kernels on one stream: the dispatch boundary provides cross-XCD
// visibility (R3-R6 lessons: per-block agent fences = L2 writeback storm
// ~125us; same-address device atomics = 23ns each serialized; memset node +
// in-kernel combine tail costs more than a second tiny dispatch).

__global__ __launch_bounds__(256, 8) void k_main(const float* __restrict__ feat,
                                                 const float* __restrict__ centers,
                                                 const int* __restrict__ label,
                                                 float* __restrict__ ws) {
    __shared__ float s_sh[4][512];
    __shared__ float d_sh[4];
    __shared__ float sm[4];
    const int t = threadIdx.x;
    const int w = t >> 6, l = t & 63;

    if (blockIdx.x < SB) {
        // ---- centers pass: row norms -> inv, s += c*inv, diag += n2*inv^2 ----
        const float4* c4 = (const float4*)centers;
        const int j0 = blockIdx.x * ROWS_PER_BLOCK;
        float4 sa = make_float4(0.f, 0.f, 0.f, 0.f);
        float4 sb = make_float4(0.f, 0.f, 0.f, 0.f);
        float diag = 0.f;
        for (int r = w; r < ROWS_PER_BLOCK; r += 4) {  // 5 rows per wave
            const int j = j0 + r;
            const float4 a = c4[j * 128 + l];
            const float4 b = c4[j * 128 + 64 + l];
            float n2 = a.x*a.x + a.y*a.y + a.z*a.z + a.w*a.w
                     + b.x*b.x + b.y*b.y + b.z*b.z + b.w*b.w;
            for (int o = 32; o > 0; o >>= 1) n2 += __shfl_xor(n2, o, 64);
            const float inv = 1.0f / fmaxf(sqrtf(n2), EPS);
            sa.x += a.x * inv; sa.y += a.y * inv; sa.z += a.z * inv; sa.w += a.w * inv;
            sb.x += b.x * inv; sb.y += b.y * inv; sb.z += b.z * inv; sb.w += b.w * inv;
            diag += n2 * inv * inv;   // identical in all lanes
        }
        s_sh[w][4*l+0] = sa.x; s_sh[w][4*l+1] = sa.y;
        s_sh[w][4*l+2] = sa.z; s_sh[w][4*l+3] = sa.w;
        s_sh[w][256+4*l+0] = sb.x; s_sh[w][256+4*l+1] = sb.y;
        s_sh[w][256+4*l+2] = sb.z; s_sh[w][256+4*l+3] = sb.w;
        if (l == 0) d_sh[w] = diag;
        __syncthreads();
        const float v0 = s_sh[0][t] + s_sh[1][t] + s_sh[2][t] + s_sh[3][t];
        const float v1 = s_sh[0][t+256] + s_sh[1][t+256] + s_sh[2][t+256] + s_sh[3][t+256];
        ws[blockIdx.x * 512 + t]       = v0;
        ws[blockIdx.x * 512 + 256 + t] = v1;
        if (t == 0)
            ws[DIAG_OFF + blockIdx.x] = d_sh[0] + d_sh[1] + d_sh[2] + d_sh[3];
    } else {
        // ---- center loss: 9 compile-time chunks, labels hoisted, unrolled ----
        const float4* f4 = (const float4*)feat;
        const float4* c4 = (const float4*)centers;
        const int tid = (blockIdx.x - SB) * 256 + t;

        int lab[NCHUNK];
#pragma unroll
        for (int k = 0; k < NCHUNK; ++k) {
            const int idx = tid + k * STRIDE;
            lab[k] = (idx < TOTAL4) ? label[idx >> 7] : 0;   // independent loads
        }
        float acc = 0.f;
#pragma unroll
        for (int k = 0; k < NCHUNK; ++k) {
            const int idx = tid + k * STRIDE;
            if (idx < TOTAL4) {
                const float4 f = f4[idx];
                const float4 c = c4[lab[k] * 128 + (idx & 127)];
                const float dx = f.x - c.x, dy = f.y - c.y,
                            dz = f.z - c.z, dw = f.w - c.w;
                acc += dx * dx + dy * dy + dz * dz + dw * dw;
            }
        }
        for (int o = 32; o > 0; o >>= 1) acc += __shfl_down(acc, o, 64);
        if (l == 0) sm[w] = acc;
        __syncthreads();
        if (t == 0) ws[CL_OFF + (blockIdx.x - SB)] = sm[0] + sm[1] + sm[2] + sm[3];
    }
}

// 1 block x 512 threads: combine everything (all terms linear in partials)
__global__ void k_final(const float* __restrict__ ws, float* __restrict__ out) {
    __shared__ float sm[8];
    const int t = threadIdx.x;
    const int w = t >> 6, l = t & 63;

    float val = 0.f;
    {
        float s_d = 0.f;
#pragma unroll
        for (int bb = 0; bb < SB; ++bb) s_d += ws[bb * FEAT_DIM + t];  // coalesced
        val = s_d * s_d;                        // ||s||^2 contribution (t = d)
    }
    if (t < SB) val -= ws[DIAG_OFF + t];        // minus diagonal
    val *= LAMDA;
    float clp = 0.f;
#pragma unroll
    for (int i = 0; i < CB; i += 512) {
        const int j = i + t;
        if (j < CB) clp += ws[CL_OFF + j];
    }
    val += clp * (0.5f / (float)BATCH);

    for (int o = 32; o > 0; o >>= 1) val += __shfl_down(val, o, 64);
    if (l == 0) sm[w] = val;
    __syncthreads();
    if (t == 0)
        out[0] = sm[0] + sm[1] + sm[2] + sm[3] + sm[4] + sm[5] + sm[6] + sm[7]
               + LAMDA * (float)NUM_CLASSES * (float)(NUM_CLASSES - 1);
}

extern "C" void kernel_launch(void* const* d_in, const int* in_sizes, int n_in,
                              void* d_out, int out_size, void* d_ws, size_t ws_size,
                              hipStream_t stream) {
    const int*   label   = (const int*)d_in[0];
    const float* feat    = (const float*)d_in[1];
    const float* centers = (const float*)d_in[2];
    float* ws  = (float*)d_ws;
    float* out = (float*)d_out;

    k_main<<<GRID, 256, 0, stream>>>(feat, centers, label, ws);
    k_final<<<1, 512, 0, stream>>>(ws, out);
}

// Round 8
// 21.176 us; speedup vs baseline: 11.0818x; 1.1721x over previous
//
#include <hip/hip_runtime.h>
#include <math.h>

#define NUM_CLASSES 1000
#define FEAT_DIM    512
#define BATCH       32768
#define LAMDA       0.5f
#define EPS         1e-8f

// GRID = 2048 exactly: 8 blocks/CU x 256 CU -> one residency round.
#define SB   25               // centers-pass blocks
#define CB   2023             // streaming center-loss blocks
#define GRID (SB + CB)        // 2048
#define ROWS_PER_BLOCK 40     // 25*40 = 1000 center rows
#define TOTAL4  (BATCH * FEAT_DIM / 4)   // 4194304 float4s
#define STRIDE  (CB * 256)               // 517888
// chunks 0..7 always in bounds: 517887 + 7*517888 = 4143103 < 4194304
// chunk 8 predicated: only tid < 51200 participates

// ws layout (floats):
//   [0, 25*512)      s partials (per centers-block weighted column sums)
#define DIAG_OFF 25600   // [25600, 25625)  diag partials
#define CL_OFF   26624   // [26624, 26624+CB) center-loss partials

// Two plain kernels; dispatch boundary = cross-XCD visibility (R3-R6 lessons:
// agent fences -> L2 writeback storm ~125us; same-address device atomics
// serialize at ~23ns; completion machinery costs more than a tiny dispatch).

__global__ __launch_bounds__(256, 8) void k_main(const float* __restrict__ feat,
                                                 const float* __restrict__ centers,
                                                 const int* __restrict__ label,
                                                 float* __restrict__ ws) {
    __shared__ float s_sh[4][512];
    __shared__ float d_sh[4];
    __shared__ float sm[4];
    const int t = threadIdx.x;
    const int w = t >> 6, l = t & 63;

    if (blockIdx.x < SB) {
        // ---- centers pass: row norms -> inv, s += c*inv, diag += n2*inv^2 ----
        const float4* c4 = (const float4*)centers;
        const int j0 = blockIdx.x * ROWS_PER_BLOCK;
        float4 sa = make_float4(0.f, 0.f, 0.f, 0.f);
        float4 sb = make_float4(0.f, 0.f, 0.f, 0.f);
        float diag = 0.f;
        for (int r = w; r < ROWS_PER_BLOCK; r += 4) {  // 10 rows per wave
            const int j = j0 + r;
            const float4 a = c4[j * 128 + l];
            const float4 b = c4[j * 128 + 64 + l];
            float n2 = a.x*a.x + a.y*a.y + a.z*a.z + a.w*a.w
                     + b.x*b.x + b.y*b.y + b.z*b.z + b.w*b.w;
            for (int o = 32; o > 0; o >>= 1) n2 += __shfl_xor(n2, o, 64);
            const float inv = 1.0f / fmaxf(sqrtf(n2), EPS);
            sa.x += a.x * inv; sa.y += a.y * inv; sa.z += a.z * inv; sa.w += a.w * inv;
            sb.x += b.x * inv; sb.y += b.y * inv; sb.z += b.z * inv; sb.w += b.w * inv;
            diag += n2 * inv * inv;   // identical in all lanes
        }
        s_sh[w][4*l+0] = sa.x; s_sh[w][4*l+1] = sa.y;
        s_sh[w][4*l+2] = sa.z; s_sh[w][4*l+3] = sa.w;
        s_sh[w][256+4*l+0] = sb.x; s_sh[w][256+4*l+1] = sb.y;
        s_sh[w][256+4*l+2] = sb.z; s_sh[w][256+4*l+3] = sb.w;
        if (l == 0) d_sh[w] = diag;
        __syncthreads();
        const float v0 = s_sh[0][t] + s_sh[1][t] + s_sh[2][t] + s_sh[3][t];
        const float v1 = s_sh[0][t+256] + s_sh[1][t+256] + s_sh[2][t+256] + s_sh[3][t+256];
        ws[blockIdx.x * 512 + t]       = v0;
        ws[blockIdx.x * 512 + 256 + t] = v1;
        if (t == 0)
            ws[DIAG_OFF + blockIdx.x] = d_sh[0] + d_sh[1] + d_sh[2] + d_sh[3];
    } else {
        // ---- center loss: 8 unconditional chunks + 1 predicated ----
        const float4* f4 = (const float4*)feat;
        const float4* c4 = (const float4*)centers;
        const int tid = (blockIdx.x - SB) * 256 + t;

        int lab[9];
#pragma unroll
        for (int k = 0; k < 8; ++k)
            lab[k] = label[(tid + k * STRIDE) >> 7];   // independent loads
        const int idx8 = tid + 8 * STRIDE;
        lab[8] = (idx8 < TOTAL4) ? label[idx8 >> 7] : 0;

        float acc = 0.f;
#pragma unroll
        for (int k = 0; k < 8; ++k) {
            const int idx = tid + k * STRIDE;
            const float4 f = f4[idx];
            const float4 c = c4[lab[k] * 128 + (idx & 127)];
            const float dx = f.x - c.x, dy = f.y - c.y,
                        dz = f.z - c.z, dw = f.w - c.w;
            acc += dx * dx + dy * dy + dz * dz + dw * dw;
        }
        if (idx8 < TOTAL4) {
            const float4 f = f4[idx8];
            const float4 c = c4[lab[8] * 128 + (idx8 & 127)];
            const float dx = f.x - c.x, dy = f.y - c.y,
                        dz = f.z - c.z, dw = f.w - c.w;
            acc += dx * dx + dy * dy + dz * dz + dw * dw;
        }
        for (int o = 32; o > 0; o >>= 1) acc += __shfl_down(acc, o, 64);
        if (l == 0) sm[w] = acc;
        __syncthreads();
        if (t == 0) ws[CL_OFF + (blockIdx.x - SB)] = sm[0] + sm[1] + sm[2] + sm[3];
    }
}

// 1 block x 1024 threads: combine everything (all terms linear in partials)
__global__ __launch_bounds__(1024) void k_final(const float* __restrict__ ws,
                                                float* __restrict__ out) {
    __shared__ float sm[16];
    const int t = threadIdx.x;
    const int w = t >> 6, l = t & 63;

    float island = 0.f;
    if (t < 128) {
        // ||s||^2: thread t handles columns 4t..4t+3 as float4
        float4 sq = make_float4(0.f, 0.f, 0.f, 0.f);
#pragma unroll
        for (int bb = 0; bb < SB; ++bb) {
            const float4 p = ((const float4*)(ws + bb * FEAT_DIM))[t];
            sq.x += p.x; sq.y += p.y; sq.z += p.z; sq.w += p.w;
        }
        island = sq.x*sq.x + sq.y*sq.y + sq.z*sq.z + sq.w*sq.w;
    } else if (t < 128 + SB) {
        island = -ws[DIAG_OFF + (t - 128)];          // minus diagonal
    }

    float cl = ws[CL_OFF + t < CL_OFF + CB ? CL_OFF + t : CL_OFF];  // placeholder avoided below
    // (rewritten cleanly:)
    cl = (t < CB) ? ws[CL_OFF + t] : 0.f;
    if (t + 1024 < CB) cl += ws[CL_OFF + t + 1024];

    float val = LAMDA * island + cl * (0.5f / (float)BATCH);

    for (int o = 32; o > 0; o >>= 1) val += __shfl_down(val, o, 64);
    if (l == 0) sm[w] = val;
    __syncthreads();
    if (w == 0) {
        float v = (l < 16) ? sm[l] : 0.f;
        for (int o = 8; o > 0; o >>= 1) v += __shfl_down(v, o, 64);
        if (l == 0)
            out[0] = v + LAMDA * (float)NUM_CLASSES * (float)(NUM_CLASSES - 1);
    }
}

extern "C" void kernel_launch(void* const* d_in, const int* in_sizes, int n_in,
                              void* d_out, int out_size, void* d_ws, size_t ws_size,
                              hipStream_t stream) {
    const int*   label   = (const int*)d_in[0];
    const float* feat    = (const float*)d_in[1];
    const float* centers = (const float*)d_in[2];
    float* ws  = (float*)d_ws;
    float* out = (float*)d_out;

    k_main<<<GRID, 256, 0, stream>>>(feat, centers, label, ws);
    k_final<<<1, 1024, 0, stream>>>(ws, out);
}